// Round 6
// baseline (453.678 us; speedup 1.0000x reference)
//
#include <hip/hip_runtime.h>
#include <hip/hip_bf16.h>

#define DIM  256
#define NSEQ 8192
#define BATCH 8
#define WIN  512

typedef __attribute__((ext_vector_type(8))) short short8;   // bf16x8 MFMA frag (4 VGPRs)
typedef __attribute__((ext_vector_type(4))) float floatx4;  // MFMA acc

union PFU { int i[4]; short8 v; };

__device__ __forceinline__ int packbf(float a, float b) {
    __hip_bfloat162 h;
    h.x = __float2bfloat16(a);
    h.y = __float2bfloat16(b);
    int r;
    __builtin_memcpy(&r, &h, 4);
    return r;
}

// ---------------------------------------------------------------------------
// Kernel 1 (R10): FUSED transpose + W-cast + 3-mode projection.
// W fragments are read as f32 straight from the input weights (L2-resident,
// 768 KB) and converted inline (4 packbf per fragment).
// ---------------------------------------------------------------------------
__global__ __launch_bounds__(256, 3) void k_prep(const float* __restrict__ x,
                                                 const float* __restrict__ Wq,
                                                 const float* __restrict__ Wk,
                                                 const float* __restrict__ Wv,
                                                 const float* __restrict__ bq,
                                                 const float* __restrict__ bk,
                                                 const float* __restrict__ bv,
                                                 __hip_bfloat16* __restrict__ qo,
                                                 __hip_bfloat16* __restrict__ ko,
                                                 __hip_bfloat16* __restrict__ vto) {
    __shared__ float ftile[64][68];                 // 17.4 KB, padded (16B-aligned rows)
    __shared__ __align__(16) char As[32768];        // 32 KB bf16 A-tile, seg-major
    const int b   = blockIdx.y;
    const int n0  = blockIdx.x * 64;
    const int tid = threadIdx.x;
    const int wv  = tid >> 6;
    const int l   = tid & 63;
    const int lm  = l & 15;
    const int qd  = l >> 4;
    const int wn  = wv * 64;   // this wave's 64-col slice (Phase B)

    const float* xb = x + (size_t)b * DIM * NSEQ;

    // ---- Phase A: transpose+convert 256d x 64n of x into As ----
    const int dr = l >> 4, nseg = l & 15;
#pragma unroll
    for (int dsl = 0; dsl < 4; ++dsl) {
        const int d0 = dsl * 64;
#pragma unroll
        for (int i = 0; i < 4; ++i) {
            const int r = wv * 16 + i * 4 + dr;
            float4 v = *(const float4*)(xb + (size_t)(d0 + r) * NSEQ + n0 + nseg * 4);
            *(float4*)&ftile[r][nseg * 4] = v;
        }
        __syncthreads();
#pragma unroll
        for (int p = 0; p < 2; ++p) {
            const int ks = dsl * 2 + p;
            int4 pk;
            int* pki = (int*)&pk;
#pragma unroll
            for (int jj = 0; jj < 4; ++jj)
                pki[jj] = packbf(ftile[p * 32 + wv * 8 + jj * 2][l],
                                 ftile[p * 32 + wv * 8 + jj * 2 + 1][l]);
            *(int4*)(As + ks * 4096 + wv * 1024 + l * 16) = pk;
        }
        __syncthreads();
    }

    // ---- Phase B: 3 projection GEMMs from As ----
#pragma unroll
    for (int mode = 0; mode < 3; ++mode) {
        const float* wsrc = (mode == 0) ? Wq : ((mode == 1) ? Wk : Wv);
        floatx4 acc[4][4];
#pragma unroll
        for (int i = 0; i < 4; ++i)
#pragma unroll
            for (int j = 0; j < 4; ++j) acc[i][j] = (floatx4){0.f, 0.f, 0.f, 0.f};

#pragma unroll
        for (int ks = 0; ks < 8; ++ks) {
            short8 wf[4], af[4];
#pragma unroll
            for (int j = 0; j < 4; ++j) {
                const float* wr = wsrc + (size_t)(wn + j * 16 + lm) * 256 + ks * 32 + qd * 8;
                float4 wa = *(const float4*)wr;
                float4 wc = *(const float4*)(wr + 4);
                PFU pw;
                pw.i[0] = packbf(wa.x, wa.y);
                pw.i[1] = packbf(wa.z, wa.w);
                pw.i[2] = packbf(wc.x, wc.y);
                pw.i[3] = packbf(wc.z, wc.w);
                wf[j] = pw.v;
            }
#pragma unroll
            for (int j = 0; j < 4; ++j)
                af[j] = *(const short8*)(As + ks * 4096 + qd * 1024 + (j * 16 + lm) * 16);
            if (mode < 2) {
#pragma unroll
                for (int mt = 0; mt < 4; ++mt)
#pragma unroll
                    for (int nt = 0; nt < 4; ++nt)
                        acc[mt][nt] = __builtin_amdgcn_mfma_f32_16x16x32_bf16(af[mt], wf[nt], acc[mt][nt], 0, 0, 0);
            } else {
#pragma unroll
                for (int jw = 0; jw < 4; ++jw)
#pragma unroll
                    for (int ja = 0; ja < 4; ++ja)
                        acc[jw][ja] = __builtin_amdgcn_mfma_f32_16x16x32_bf16(wf[jw], af[ja], acc[jw][ja], 0, 0, 0);
            }
        }

        if (mode < 2) {
            const float* bias = mode ? bk : bq;
            __hip_bfloat16* op = (mode ? ko : qo) + (size_t)b * NSEQ * DIM;
            float bc[4];
#pragma unroll
            for (int nt = 0; nt < 4; ++nt) bc[nt] = bias[wn + nt * 16 + lm];
#pragma unroll
            for (int mt = 0; mt < 4; ++mt)
#pragma unroll
                for (int nt = 0; nt < 4; ++nt)
#pragma unroll
                    for (int r = 0; r < 4; ++r)
                        op[(size_t)(n0 + mt * 16 + qd * 4 + r) * DIM + wn + nt * 16 + lm] =
                            __float2bfloat16(acc[mt][nt][r] + bc[nt]);
        } else {
            __hip_bfloat16* op = vto + (size_t)b * DIM * NSEQ;
#pragma unroll
            for (int jw = 0; jw < 4; ++jw)
#pragma unroll
                for (int r = 0; r < 4; ++r) {
                    const int d = wn + jw * 16 + qd * 4 + r;
                    const float bb = bv[d];
#pragma unroll
                    for (int ja = 0; ja < 4; ++ja)
                        op[(size_t)d * NSEQ + n0 + ja * 16 + lm] =
                            __float2bfloat16(acc[jw][ja][r] + bb);
                }
        }
    }
}

// ---------------------------------------------------------------------------
// Kernel 2 (R10): flash attention, TRIPLE-buffered + T15 QK-ahead pipeline.
// 3 LDS slots (96 KB, 1 block/CU which the 256-block grid forces anyway).
// Chunk c+1's K is resident during chunk c, so QK(c+1) is issued BEFORE
// softmax(c): its LDS reads + MFMAs fill the matrix/LDS pipes while the
// wave issues the softmax VALU/trans chain for st_cur (T15 mechanism).
// Buffer safety: iter c writes slot fut=cur(c-1), whose last reader
// (chunk c-1) finished before iter (c-1)'s barrier; QK(c+1) reads the slot
// staged in iter c-1, also barrier-protected. One barrier per chunk.
// st_cur/st_next are explicit two-state (static indexing, rule #20).
// ---------------------------------------------------------------------------
__global__ __launch_bounds__(512, 2) void k_attn(const __hip_bfloat16* __restrict__ qm,
                                                 const __hip_bfloat16* __restrict__ km,
                                                 const __hip_bfloat16* __restrict__ vtm,
                                                 const float* __restrict__ x,
                                                 float* __restrict__ out) {
    __shared__ __align__(16) char kbuf[3][16384];
    __shared__ __align__(16) char vbuf[3][16384];

    const int w  = blockIdx.x, b = blockIdx.y, qt = blockIdx.z;
    const int tid = threadIdx.x;
    const int wv = tid >> 6;
    const int l  = tid & 63;
    const int m  = l & 15;   // q-row (and fragment row) within 16
    const int qd = l >> 4;   // quad

    const int qbw   = qt * 256 + wv * 32;  // wave q-base within window [0,512)
    const int koff0 = w * WIN - WIN;       // global row of key_local 0

    // ---- Q fragments for both q-tiles (private, once) ----
    short8 qf[2][8];
#pragma unroll
    for (int u = 0; u < 2; ++u) {
        const __hip_bfloat16* qrow =
            qm + ((size_t)b * NSEQ + (size_t)(w * WIN + qbw + u * 16 + m)) * DIM;
#pragma unroll
        for (int s = 0; s < 8; ++s)
            qf[u][s] = *(const short8*)(qrow + s * 32 + qd * 8);
    }

    const char* kbase = (const char*)(km + (size_t)b * NSEQ * DIM);
    const char* vbase = (const char*)(vtm + (size_t)b * DIM * NSEQ);

    const int c0  = (w == 0) ? 16 : 0;               // skip nonexistent prev window
    const int c1w = (512 + qbw + 63) >> 5;           // per-wave exclusive chunk end
    const int c1b = (799 + qt * 256) >> 5;           // block-level end (top wave)

    // ---- staging role ----
    const bool   isK     = wv < 4;
    const size_t gstride = isK ? (size_t)64 : (size_t)16 * NSEQ * 2;   // i-step
    const size_t adv     = isK ? (size_t)32 * 512 : (size_t)64;        // chunk-step
    const int    lbase   = (isK ? wv * 4 : (wv - 4) * 4) * 1024 + l * 16;
    const char* gp0;
    if (isK)
        gp0 = kbase + (size_t)(koff0 + c0 * 32 + (wv >> 1) * 16 + m) * 512 +
              (size_t)((wv & 1) * 16 + qd) * 16;
    else
        gp0 = vbase + (size_t)((wv - 4) * 64 + m) * (NSEQ * 2) +
              (size_t)(koff0 + c0 * 32) * 2 + (size_t)qd * 16;

    floatx4 o[2][16];
#pragma unroll
    for (int u = 0; u < 2; ++u)
#pragma unroll
        for (int t = 0; t < 16; ++t) o[u][t] = (floatx4){0.f, 0.f, 0.f, 0.f};
    float mi[2] = {-INFINITY, -INFINITY};
    float li[2] = {0.f, 0.f};
    const float sscale = 0.0625f * 1.4426950408889634f;  // D^-0.5 * log2(e)

    const int a0 = (((qd & 1) * 2) * 16 + m) * 4;  // bpermute byte addrs
    const int a1 = a0 + 64;
    const bool hi = (qd >> 1) != 0;

    // QK helper: S^T = K · Q^T, both q-tiles per kf read (2x reuse)
    auto QK = [&](const char* kbp, floatx4 (&stt)[2][2]) {
#pragma unroll
        for (int u = 0; u < 2; ++u)
#pragma unroll
            for (int t = 0; t < 2; ++t) stt[u][t] = (floatx4){0.f, 0.f, 0.f, 0.f};
        __builtin_amdgcn_s_setprio(1);   // T5
#pragma unroll
        for (int t = 0; t < 2; ++t)
#pragma unroll
            for (int s = 0; s < 8; ++s) {
                short8 kf = *(const short8*)(kbp + ((t * 8 + s) * 64 + l) * 16);
                stt[0][t] = __builtin_amdgcn_mfma_f32_16x16x32_bf16(kf, qf[0][s], stt[0][t], 0, 0, 0);
                stt[1][t] = __builtin_amdgcn_mfma_f32_16x16x32_bf16(kf, qf[1][s], stt[1][t], 0, 0, 0);
            }
        __builtin_amdgcn_s_setprio(0);
    };

    // ---- prologue: stage chunk c0 -> slot 0, chunk c0+1 -> slot 1 ----
    int4 rg[4];
#pragma unroll
    for (int i = 0; i < 4; ++i)
        rg[i] = *(const int4*)(gp0 + (size_t)i * gstride);
    gp0 += adv;
    {
        char* d0 = (isK ? kbuf[0] : vbuf[0]) + lbase;
#pragma unroll
        for (int i = 0; i < 4; ++i)
            *(int4*)(d0 + i * 1024) = rg[i];
    }
#pragma unroll
    for (int i = 0; i < 4; ++i)
        rg[i] = *(const int4*)(gp0 + (size_t)i * gstride);
    gp0 += adv;
    {
        char* d1 = (isK ? kbuf[1] : vbuf[1]) + lbase;
#pragma unroll
        for (int i = 0; i < 4; ++i)
            *(int4*)(d1 + i * 1024) = rg[i];
    }
    __syncthreads();  // slots 0,1 ready

    floatx4 stc[2][2], stn[2][2];
    QK(kbuf[0], stc);                 // scores for chunk c0 (c0 < c1w always)

    int cur = 0, nxt = 1, fut = 2;
    for (int c = c0; c < c1b; ++c) {
        const bool more2 = (c + 2 < c1b);
        // ---- issue global loads for chunk c+2 (in flight during compute) ----
        if (more2) {
#pragma unroll
            for (int i = 0; i < 4; ++i)
                rg[i] = *(const int4*)(gp0 + (size_t)i * gstride);
            gp0 += adv;
        }
        if (c < c1w) {
            // ---- QK(c+1) ahead: MFMAs/LDS reads overlap softmax(c) VALU ----
            const bool nn = (c + 1 < c1w);
            if (nn) QK(kbuf[nxt], stn);

            // ---- softmax(c) on stc ----
            const int kl0 = c * 32;
            short8 pf[2];
#pragma unroll
            for (int u = 0; u < 2; ++u) {
                const int lim = 512 + qbw + u * 16 + m;
                const bool needmask = (kl0 + 31) > lim;
                float p[8];
#pragma unroll
                for (int t = 0; t < 2; ++t)
#pragma unroll
                    for (int r = 0; r < 4; ++r) {
                        float v = stc[u][t][r] * sscale;
                        if (needmask) {
                            int key = kl0 + t * 16 + qd * 4 + r;
                            v = (key <= lim) ? v : -INFINITY;
                        }
                        p[t * 4 + r] = v;
                    }
                float mx = p[0];
#pragma unroll
                for (int i = 1; i < 8; ++i) mx = fmaxf(mx, p[i]);
                mx = fmaxf(mx, __shfl_xor(mx, 16, 64));
                mx = fmaxf(mx, __shfl_xor(mx, 32, 64));
                // T13 defer-max: if tile max grew <= 8 wave-wide, keep m_old.
                float mnew;
                if (__all(mx <= mi[u] + 8.0f)) mnew = mi[u];
                else                           mnew = fmaxf(mi[u], mx);
                const float alpha = exp2f(mi[u] - mnew);
                float ps = 0.f;
#pragma unroll
                for (int i = 0; i < 8; ++i) { p[i] = exp2f(p[i] - mnew); ps += p[i]; }
                ps += __shfl_xor(ps, 16, 64);
                ps += __shfl_xor(ps, 32, 64);
                li[u] = li[u] * alpha + ps;
                mi[u] = mnew;
                if (!__all(alpha == 1.0f)) {   // alpha==1 multiply is exact -> safe skip
#pragma unroll
                    for (int t = 0; t < 16; ++t) {
                        o[u][t][0] *= alpha; o[u][t][1] *= alpha;
                        o[u][t][2] *= alpha; o[u][t][3] *= alpha;
                    }
                }
                // pack P^T (bf16) + quad shuffle into B-fragment layout
                int pd0 = packbf(p[0], p[1]);
                int pd1 = packbf(p[2], p[3]);
                int pd2 = packbf(p[4], p[5]);
                int pd3 = packbf(p[6], p[7]);
                int x0 = __builtin_amdgcn_ds_bpermute(a0, pd0);
                int y0 = __builtin_amdgcn_ds_bpermute(a0, pd2);
                int x1 = __builtin_amdgcn_ds_bpermute(a0, pd1);
                int y1 = __builtin_amdgcn_ds_bpermute(a0, pd3);
                int x2 = __builtin_amdgcn_ds_bpermute(a1, pd0);
                int y2 = __builtin_amdgcn_ds_bpermute(a1, pd2);
                int x3 = __builtin_amdgcn_ds_bpermute(a1, pd1);
                int y3 = __builtin_amdgcn_ds_bpermute(a1, pd3);
                PFU pu;
                pu.i[0] = hi ? y0 : x0;
                pu.i[1] = hi ? y1 : x1;
                pu.i[2] = hi ? y2 : x2;
                pu.i[3] = hi ? y3 : x3;
                pf[u] = pu.v;
            }
            // ---- PV(c): O^T += V^T · P^T ----
            const char* vbp = vbuf[cur];
            __builtin_amdgcn_s_setprio(1);   // T5
#pragma unroll
            for (int t = 0; t < 16; ++t) {
                short8 vf = *(const short8*)(vbp + (t * 64 + l) * 16);
                o[0][t] = __builtin_amdgcn_mfma_f32_16x16x32_bf16(vf, pf[0], o[0][t], 0, 0, 0);
                o[1][t] = __builtin_amdgcn_mfma_f32_16x16x32_bf16(vf, pf[1], o[1][t], 0, 0, 0);
            }
            __builtin_amdgcn_s_setprio(0);
            if (nn) {
#pragma unroll
                for (int u = 0; u < 2; ++u)
#pragma unroll
                    for (int t = 0; t < 2; ++t) stc[u][t] = stn[u][t];
            }
        }
        // ---- stage chunk c+2 (regs -> slot fut) ----
        if (more2) {
            char* dst = (isK ? kbuf[fut] : vbuf[fut]) + lbase;
#pragma unroll
            for (int i = 0; i < 4; ++i)
                *(int4*)(dst + i * 1024) = rg[i];
        }
        __syncthreads();
        const int t0 = cur; cur = nxt; nxt = fut; fut = t0;
    }

    // ---- epilogue: O/l + residual, write out[b][d][n] (coalesced in n) ----
#pragma unroll
    for (int u = 0; u < 2; ++u) {
        const float inv = 1.f / li[u];
        const int ng = w * WIN + qbw + u * 16 + m;
        const float* xr  = x   + (size_t)b * DIM * NSEQ + ng;
        float*       orw = out + (size_t)b * DIM * NSEQ + ng;
#pragma unroll
        for (int t = 0; t < 16; ++t)
#pragma unroll
            for (int r = 0; r < 4; ++r) {
                int d = t * 16 + qd * 4 + r;
                orw[(size_t)d * NSEQ] = xr[(size_t)d * NSEQ] + o[u][t][r] * inv;
            }
    }
}

// ---------------------------------------------------------------------------
extern "C" void kernel_launch(void* const* d_in, const int* in_sizes, int n_in,
                              void* d_out, int out_size, void* d_ws, size_t ws_size,
                              hipStream_t stream) {
    const float* x  = (const float*)d_in[0];
    const float* Wq = (const float*)d_in[1];
    const float* bq = (const float*)d_in[2];
    const float* Wk = (const float*)d_in[3];
    const float* bk = (const float*)d_in[4];
    const float* Wv = (const float*)d_in[5];
    const float* bv = (const float*)d_in[6];

    char* ws = (char*)d_ws;
    const size_t SZ = (size_t)BATCH * NSEQ * DIM * sizeof(__hip_bfloat16);  // 32 MB
    __hip_bfloat16* qb_ = (__hip_bfloat16*)(ws);
    __hip_bfloat16* kb_ = (__hip_bfloat16*)(ws + SZ);
    __hip_bfloat16* vt_ = (__hip_bfloat16*)(ws + 2 * SZ);

    k_prep<<<dim3(NSEQ / 64, BATCH), 256, 0, stream>>>(x, Wq, Wk, Wv, bq, bk, bv, qb_, kb_, vt_);
    k_attn<<<dim3(16, BATCH, 2), 512, 0, stream>>>(qb_, kb_, vt_, x, (float*)d_out);
}

// Round 7
// 336.112 us; speedup vs baseline: 1.3498x; 1.3498x over previous
//
#include <hip/hip_runtime.h>
#include <hip/hip_bf16.h>

#define DIM  256
#define NSEQ 8192
#define BATCH 8
#define WIN  512

typedef __attribute__((ext_vector_type(8))) short short8;   // bf16x8 MFMA frag (4 VGPRs)
typedef __attribute__((ext_vector_type(4))) float floatx4;  // MFMA acc

union PFU { int i[4]; short8 v; };

__device__ __forceinline__ int packbf(float a, float b) {
    __hip_bfloat162 h;
    h.x = __float2bfloat16(a);
    h.y = __float2bfloat16(b);
    int r;
    __builtin_memcpy(&r, &h, 4);
    return r;
}

// ---------------------------------------------------------------------------
// Kernel 1: Wq,Wk,Wv f32 -> packed bf16 buffer wb[3][256*256]  (R9 revert:
// precomputing the cast once beats per-block inline conversion, R10 lesson)
// ---------------------------------------------------------------------------
__global__ __launch_bounds__(256) void k_wcast(const float* __restrict__ w0,
                                               const float* __restrict__ w1,
                                               const float* __restrict__ w2,
                                               __hip_bfloat16* __restrict__ wb) {
    int i = (blockIdx.x * 256 + threadIdx.x) * 4;
    const float* s = (i < 65536) ? (w0 + i) : ((i < 131072) ? (w1 + i - 65536) : (w2 + i - 131072));
    float4 v = *(const float4*)s;
    union { __hip_bfloat16 h[4]; ushort4 u; } cv;
    cv.h[0] = __float2bfloat16(v.x);
    cv.h[1] = __float2bfloat16(v.y);
    cv.h[2] = __float2bfloat16(v.z);
    cv.h[3] = __float2bfloat16(v.w);
    *(ushort4*)(wb + i) = cv.u;
}

// ---------------------------------------------------------------------------
// Kernel 2 (R9 revert, verified 347.6 us config): FUSED transpose + 3-mode
// projection, W read as bf16 from wb (L2-resident).
// ---------------------------------------------------------------------------
__global__ __launch_bounds__(256, 3) void k_prep(const float* __restrict__ x,
                                                 const __hip_bfloat16* __restrict__ wb,
                                                 const float* __restrict__ bq,
                                                 const float* __restrict__ bk,
                                                 const float* __restrict__ bv,
                                                 __hip_bfloat16* __restrict__ qo,
                                                 __hip_bfloat16* __restrict__ ko,
                                                 __hip_bfloat16* __restrict__ vto) {
    __shared__ float ftile[64][68];                 // 17.4 KB, padded (16B-aligned rows)
    __shared__ __align__(16) char As[32768];        // 32 KB bf16 A-tile, seg-major
    const int b   = blockIdx.y;
    const int n0  = blockIdx.x * 64;
    const int tid = threadIdx.x;
    const int wv  = tid >> 6;
    const int l   = tid & 63;
    const int lm  = l & 15;
    const int qd  = l >> 4;
    const int wn  = wv * 64;   // this wave's 64-col slice (Phase B)

    const float* xb = x + (size_t)b * DIM * NSEQ;

    // ---- Phase A: transpose+convert 256d x 64n of x into As ----
    const int dr = l >> 4, nseg = l & 15;
#pragma unroll
    for (int dsl = 0; dsl < 4; ++dsl) {
        const int d0 = dsl * 64;
#pragma unroll
        for (int i = 0; i < 4; ++i) {
            const int r = wv * 16 + i * 4 + dr;
            float4 v = *(const float4*)(xb + (size_t)(d0 + r) * NSEQ + n0 + nseg * 4);
            *(float4*)&ftile[r][nseg * 4] = v;
        }
        __syncthreads();
#pragma unroll
        for (int p = 0; p < 2; ++p) {
            const int ks = dsl * 2 + p;
            int4 pk;
            int* pki = (int*)&pk;
#pragma unroll
            for (int jj = 0; jj < 4; ++jj)
                pki[jj] = packbf(ftile[p * 32 + wv * 8 + jj * 2][l],
                                 ftile[p * 32 + wv * 8 + jj * 2 + 1][l]);
            *(int4*)(As + ks * 4096 + wv * 1024 + l * 16) = pk;
        }
        __syncthreads();
    }

    // ---- Phase B: 3 projection GEMMs from As ----
#pragma unroll
    for (int mode = 0; mode < 3; ++mode) {
        const __hip_bfloat16* wp = wb + mode * 65536;
        floatx4 acc[4][4];
#pragma unroll
        for (int i = 0; i < 4; ++i)
#pragma unroll
            for (int j = 0; j < 4; ++j) acc[i][j] = (floatx4){0.f, 0.f, 0.f, 0.f};

#pragma unroll
        for (int ks = 0; ks < 8; ++ks) {
            short8 wf[4], af[4];
#pragma unroll
            for (int j = 0; j < 4; ++j)
                wf[j] = *(const short8*)(wp + (size_t)(wn + j * 16 + lm) * DIM + ks * 32 + qd * 8);
#pragma unroll
            for (int j = 0; j < 4; ++j)
                af[j] = *(const short8*)(As + ks * 4096 + qd * 1024 + (j * 16 + lm) * 16);
            if (mode < 2) {
#pragma unroll
                for (int mt = 0; mt < 4; ++mt)
#pragma unroll
                    for (int nt = 0; nt < 4; ++nt)
                        acc[mt][nt] = __builtin_amdgcn_mfma_f32_16x16x32_bf16(af[mt], wf[nt], acc[mt][nt], 0, 0, 0);
            } else {
#pragma unroll
                for (int jw = 0; jw < 4; ++jw)
#pragma unroll
                    for (int ja = 0; ja < 4; ++ja)
                        acc[jw][ja] = __builtin_amdgcn_mfma_f32_16x16x32_bf16(wf[jw], af[ja], acc[jw][ja], 0, 0, 0);
            }
        }

        if (mode < 2) {
            const float* bias = mode ? bk : bq;
            __hip_bfloat16* op = (mode ? ko : qo) + (size_t)b * NSEQ * DIM;
            float bc[4];
#pragma unroll
            for (int nt = 0; nt < 4; ++nt) bc[nt] = bias[wn + nt * 16 + lm];
#pragma unroll
            for (int mt = 0; mt < 4; ++mt)
#pragma unroll
                for (int nt = 0; nt < 4; ++nt)
#pragma unroll
                    for (int r = 0; r < 4; ++r)
                        op[(size_t)(n0 + mt * 16 + qd * 4 + r) * DIM + wn + nt * 16 + lm] =
                            __float2bfloat16(acc[mt][nt][r] + bc[nt]);
        } else {
            __hip_bfloat16* op = vto + (size_t)b * DIM * NSEQ;
#pragma unroll
            for (int jw = 0; jw < 4; ++jw)
#pragma unroll
                for (int r = 0; r < 4; ++r) {
                    const int d = wn + jw * 16 + qd * 4 + r;
                    const float bb = bv[d];
#pragma unroll
                    for (int ja = 0; ja < 4; ++ja)
                        op[(size_t)d * NSEQ + n0 + ja * 16 + lm] =
                            __float2bfloat16(acc[jw][ja][r] + bb);
                }
        }
    }
}

// ---------------------------------------------------------------------------
// Kernel 3 (R12): flash attention, 16 waves x 1 q-tile (1024 threads).
// Diagnosis (R7 counters): chunk ~15k cyc with MFMA 14% / VALU 17% / LDS
// ~20% busy -> pure latency serialization; only 2 waves/SIMD and the
// 256-reg unified file is FULL (VGPR 128 + o[2][16]=128 AGPR), so no ILP
// can be added (R10's attempt spilled). Fix: halve per-wave state
// (qf 32 + o 64 AGPR + ~35 misc ~ <=128 regs) -> __launch_bounds__(1024,4)
// = 4 waves/SIMD, 2x TLP to cover the latency chain. Block still covers
// 256 q (16 waves x 16 q) -> K/V traffic, grid, output behavior identical
// to the 174 us baseline (avoids R6's traffic poison). LDS layout and the
// kf/vf read patterns are byte-identical; staging re-split to 16 waves
// (8 K-waves + 8 V-waves, 2 x 1KB units each, same LDS image).
// T5 setprio + T13 defer-max retained.
// ---------------------------------------------------------------------------
__global__ __launch_bounds__(1024, 4) void k_attn(const __hip_bfloat16* __restrict__ qm,
                                                  const __hip_bfloat16* __restrict__ km,
                                                  const __hip_bfloat16* __restrict__ vtm,
                                                  const float* __restrict__ x,
                                                  float* __restrict__ out) {
    __shared__ __align__(16) char kbuf[2][16384];
    __shared__ __align__(16) char vbuf[2][16384];

    const int w  = blockIdx.x, b = blockIdx.y, qt = blockIdx.z;
    const int tid = threadIdx.x;
    const int wv = tid >> 6;    // 0..15
    const int l  = tid & 63;
    const int m  = l & 15;   // q-row (and fragment row) within 16
    const int qd = l >> 4;   // quad

    const int qbw   = qt * 256 + wv * 16;  // wave q-base within window [0,512)
    const int koff0 = w * WIN - WIN;       // global row of key_local 0

    // ---- Q fragments (1 q-tile, private, once) ----
    short8 qf[8];
    {
        const __hip_bfloat16* qrow =
            qm + ((size_t)b * NSEQ + (size_t)(w * WIN + qbw + m)) * DIM;
#pragma unroll
        for (int s = 0; s < 8; ++s)
            qf[s] = *(const short8*)(qrow + s * 32 + qd * 8);
    }

    const char* kbase = (const char*)(km + (size_t)b * NSEQ * DIM);
    const char* vbase = (const char*)(vtm + (size_t)b * DIM * NSEQ);

    const int c0  = (w == 0) ? 16 : 0;               // skip nonexistent prev window
    const int c1w = (512 + qbw + 47) >> 5;           // per-wave exclusive chunk end (16 rows)
    const int c1b = (799 + qt * 256) >> 5;           // block-level end (top wave wv=15)

    // ---- staging role: waves 0-7 stage K units 2wk,2wk+1; 8-15 stage V ----
    const bool   isK = wv < 8;
    const int    wk  = wv & 7;
    const size_t gstride = isK ? (size_t)64 : (size_t)16 * NSEQ * 2;   // unit-step
    const size_t adv     = isK ? (size_t)32 * 512 : (size_t)64;        // chunk-step
    const int    lbase   = wk * 2048 + l * 16;
    const char* gp0;
    if (isK)
        gp0 = kbase + (size_t)(koff0 + c0 * 32 + (wk >> 2) * 16 + m) * 512 +
              (size_t)(((wk >> 1) & 1) * 16 + qd) * 16 + (size_t)(wk & 1) * 128;
    else
        gp0 = vbase + (size_t)((wk >> 1) * 64 + (wk & 1) * 32 + m) * (NSEQ * 2) +
              (size_t)(koff0 + c0 * 32) * 2 + (size_t)qd * 16;

    floatx4 o[16];
#pragma unroll
    for (int t = 0; t < 16; ++t) o[t] = (floatx4){0.f, 0.f, 0.f, 0.f};
    float mi = -INFINITY;
    float li = 0.f;
    const float sscale = 0.0625f * 1.4426950408889634f;  // D^-0.5 * log2(e)

    const int a0 = (((qd & 1) * 2) * 16 + m) * 4;  // bpermute byte addrs
    const int a1 = a0 + 64;
    const bool hi = (qd >> 1) != 0;

    // ---- prologue: stage chunk c0 into buf[0] ----
    int4 rg[2];
#pragma unroll
    for (int i = 0; i < 2; ++i)
        rg[i] = *(const int4*)(gp0 + (size_t)i * gstride);
    gp0 += adv;
    {
        char* d0 = (isK ? kbuf[0] : vbuf[0]) + lbase;
#pragma unroll
        for (int i = 0; i < 2; ++i)
            *(int4*)(d0 + i * 1024) = rg[i];
    }
    __syncthreads();  // buf[0] ready

    int pb = 0;
    for (int c = c0; c < c1b; ++c) {
        const bool more = (c + 1 < c1b);
        // ---- issue loads for chunk c+1 (in flight during compute) ----
        if (more) {
#pragma unroll
            for (int i = 0; i < 2; ++i)
                rg[i] = *(const int4*)(gp0 + (size_t)i * gstride);
            gp0 += adv;
        }
        // ---- compute chunk c from buf[pb] ----
        if (c < c1w) {
            const char* kbp = kbuf[pb];
            // S^T = K · Q^T
            floatx4 st[2];
            st[0] = (floatx4){0.f, 0.f, 0.f, 0.f};
            st[1] = (floatx4){0.f, 0.f, 0.f, 0.f};
            __builtin_amdgcn_s_setprio(1);   // T5
#pragma unroll
            for (int t = 0; t < 2; ++t)
#pragma unroll
                for (int s = 0; s < 8; ++s) {
                    short8 kf = *(const short8*)(kbp + ((t * 8 + s) * 64 + l) * 16);
                    st[t] = __builtin_amdgcn_mfma_f32_16x16x32_bf16(kf, qf[s], st[t], 0, 0, 0);
                }
            __builtin_amdgcn_s_setprio(0);
            const int kl0 = c * 32;
            // ---- softmax ----
            const int lim = 512 + qbw + m;
            const bool needmask = (kl0 + 31) > lim;
            float p[8];
#pragma unroll
            for (int t = 0; t < 2; ++t)
#pragma unroll
                for (int r = 0; r < 4; ++r) {
                    float v = st[t][r] * sscale;
                    if (needmask) {
                        int key = kl0 + t * 16 + qd * 4 + r;
                        v = (key <= lim) ? v : -INFINITY;
                    }
                    p[t * 4 + r] = v;
                }
            float mx = p[0];
#pragma unroll
            for (int i = 1; i < 8; ++i) mx = fmaxf(mx, p[i]);
            mx = fmaxf(mx, __shfl_xor(mx, 16, 64));
            mx = fmaxf(mx, __shfl_xor(mx, 32, 64));
            // T13 defer-max: if tile max grew <= 8 wave-wide, keep m_old.
            float mnew;
            if (__all(mx <= mi + 8.0f)) mnew = mi;
            else                        mnew = fmaxf(mi, mx);
            const float alpha = exp2f(mi - mnew);
            float ps = 0.f;
#pragma unroll
            for (int i = 0; i < 8; ++i) { p[i] = exp2f(p[i] - mnew); ps += p[i]; }
            ps += __shfl_xor(ps, 16, 64);
            ps += __shfl_xor(ps, 32, 64);
            li = li * alpha + ps;
            mi = mnew;
            if (!__all(alpha == 1.0f)) {   // alpha==1 multiply is exact -> safe skip
#pragma unroll
                for (int t = 0; t < 16; ++t) {
                    o[t][0] *= alpha; o[t][1] *= alpha;
                    o[t][2] *= alpha; o[t][3] *= alpha;
                }
            }
            // pack P^T (bf16) + quad shuffle into B-fragment layout
            int pd0 = packbf(p[0], p[1]);
            int pd1 = packbf(p[2], p[3]);
            int pd2 = packbf(p[4], p[5]);
            int pd3 = packbf(p[6], p[7]);
            int x0 = __builtin_amdgcn_ds_bpermute(a0, pd0);
            int y0 = __builtin_amdgcn_ds_bpermute(a0, pd2);
            int x1 = __builtin_amdgcn_ds_bpermute(a0, pd1);
            int y1 = __builtin_amdgcn_ds_bpermute(a0, pd3);
            int x2 = __builtin_amdgcn_ds_bpermute(a1, pd0);
            int y2 = __builtin_amdgcn_ds_bpermute(a1, pd2);
            int x3 = __builtin_amdgcn_ds_bpermute(a1, pd1);
            int y3 = __builtin_amdgcn_ds_bpermute(a1, pd3);
            PFU pu;
            pu.i[0] = hi ? y0 : x0;
            pu.i[1] = hi ? y1 : x1;
            pu.i[2] = hi ? y2 : x2;
            pu.i[3] = hi ? y3 : x3;
            short8 pf = pu.v;
            // ---- PV: O^T += V^T · P^T ----
            const char* vbp = vbuf[pb];
            __builtin_amdgcn_s_setprio(1);   // T5
#pragma unroll
            for (int t = 0; t < 16; ++t) {
                short8 vf = *(const short8*)(vbp + (t * 64 + l) * 16);
                o[t] = __builtin_amdgcn_mfma_f32_16x16x32_bf16(vf, pf, o[t], 0, 0, 0);
            }
            __builtin_amdgcn_s_setprio(0);
        }
        // ---- stage chunk c+1 (regs -> buf[pb^1]) ----
        if (more) {
            char* dst = (isK ? kbuf[pb ^ 1] : vbuf[pb ^ 1]) + lbase;
#pragma unroll
            for (int i = 0; i < 2; ++i)
                *(int4*)(dst + i * 1024) = rg[i];
        }
        __syncthreads();
        pb ^= 1;
    }

    // ---- epilogue: O/l + residual, write out[b][d][n] (coalesced in n) ----
    {
        const float inv = 1.f / li;
        const int ng = w * WIN + qbw + m;
        const float* xr  = x   + (size_t)b * DIM * NSEQ + ng;
        float*       orw = out + (size_t)b * DIM * NSEQ + ng;
#pragma unroll
        for (int t = 0; t < 16; ++t)
#pragma unroll
            for (int r = 0; r < 4; ++r) {
                int d = t * 16 + qd * 4 + r;
                orw[(size_t)d * NSEQ] = xr[(size_t)d * NSEQ] + o[t][r] * inv;
            }
    }
}

// ---------------------------------------------------------------------------
extern "C" void kernel_launch(void* const* d_in, const int* in_sizes, int n_in,
                              void* d_out, int out_size, void* d_ws, size_t ws_size,
                              hipStream_t stream) {
    const float* x  = (const float*)d_in[0];
    const float* Wq = (const float*)d_in[1];
    const float* bq = (const float*)d_in[2];
    const float* Wk = (const float*)d_in[3];
    const float* bk = (const float*)d_in[4];
    const float* Wv = (const float*)d_in[5];
    const float* bv = (const float*)d_in[6];

    char* ws = (char*)d_ws;
    const size_t SZ = (size_t)BATCH * NSEQ * DIM * sizeof(__hip_bfloat16);  // 32 MB
    __hip_bfloat16* qb_ = (__hip_bfloat16*)(ws);
    __hip_bfloat16* kb_ = (__hip_bfloat16*)(ws + SZ);
    __hip_bfloat16* vt_ = (__hip_bfloat16*)(ws + 2 * SZ);
    __hip_bfloat16* wb_ = (__hip_bfloat16*)(ws + 3 * SZ);                   // 384 KB

    k_wcast<<<dim3(192), 256, 0, stream>>>(Wq, Wk, Wv, wb_);
    k_prep<<<dim3(NSEQ / 64, BATCH), 256, 0, stream>>>(x, wb_, bq, bk, bv, qb_, kb_, vt_);
    k_attn<<<dim3(16, BATCH, 2), 1024, 0, stream>>>(qb_, kb_, vt_, x, (float*)d_out);
}